// Round 16
// baseline (479.130 us; speedup 1.0000x reference)
//
#include <hip/hip_runtime.h>
#include <stdint.h>

// ---------------------------------------------------------------------------
// HarmonicStructureDiscriminator on MI355X (gfx950)
// STFT(512/256) -> log-shift lower (KF=7) -> conv1x7(14->64)
//   -> 8x dilated conv3x3(64->64, d=1..8) -> conv3x3(64->1)
// Round 16 = R15 (476us) + last_kernel rewritten in the proven conv3 anatomy:
// (b,f)-row blocks with XCD mapping, X row staged per kh into XOR-swizzled
// LDS (34.9KB -> 4 blocks/CU), MFMA with N=16 / only n=0 populated (B frags
// pre-built fragment-major by wnorm, 18KB L1-hot).  t=256 via 5th masked
// m-tile on wave 0 (clamped in-bounds reads, masked store).
// mfma_f32_16x16x32_bf16: A[m=lane&15][k=q*8+j], B[n=lane&15][k],
// D col=lane&15,row=q*4+reg (m89/m101-verified).
// ---------------------------------------------------------------------------

typedef __attribute__((ext_vector_type(8))) short bf16x8;
typedef __attribute__((ext_vector_type(4))) float f32x4;
typedef __attribute__((ext_vector_type(4))) int   i32x4;

#define HCV 273
#define TCV 273
#define NBATCH 4

static constexpr size_t CAN_BYTES  = (size_t)NBATCH * HCV * TCV * 64 * 2;  // 38,158,848
static constexpr size_t LOWC_BYTES = (size_t)NBATCH * HCV * TCV * 16 * 2;  // 9,539,712
static constexpr size_t SPEC_BYTES = (size_t)NBATCH * 257 * 257 * 2 * 4;
static constexpr size_t W1N_BYTES  = 64 * 128 * 2;
static constexpr size_t WLN_BYTES  = 8 * 9 * 64 * 64 * 2;
static constexpr size_t WFRAG_BYTES = 8 * 9 * 2 * 4 * 512 * 2;             // 589,824
static constexpr size_t WLFRAG_BYTES = 9 * 2 * 512 * 2;                    // 18,432

static __device__ __forceinline__ unsigned short f2bf(float f) {
  union { float f; unsigned u; } v; v.f = f;
  unsigned r = v.u + 0x7FFFu + ((v.u >> 16) & 1u);   // RNE
  return (unsigned short)(r >> 16);
}
static __device__ __forceinline__ float bflo(int u) {
  union { unsigned u; float f; } v; v.u = ((unsigned)u) << 16; return v.f;
}
static __device__ __forceinline__ float bfhi(int u) {
  union { unsigned u; float f; } v; v.u = ((unsigned)u) & 0xFFFF0000u; return v.f;
}

// ---------------------------------------------------------------------------
// Zero ONLY the canvas halos (interior is fully overwritten each layer).
// 64-channel canvas [b][f][t][64].
// ---------------------------------------------------------------------------
__global__ __launch_bounds__(256) void halo_zero_kernel(unsigned short* cA,
                                                        unsigned short* cB,
                                                        unsigned short* lowC) {
  int idx = blockIdx.x * 256 + threadIdx.x;
  if (idx >= NBATCH * HCV * TCV) return;
  int pos = idx % (HCV * TCV);
  int row = pos / TCV, col = pos % TCV;
  bool halo = (row < 8) | (row > 264) | (col < 8) | (col > 264);
  if (!halo) return;
  i32x4 z = {0, 0, 0, 0};
  i32x4* a = (i32x4*)(cA + (size_t)idx * 64);
  i32x4* b = (i32x4*)(cB + (size_t)idx * 64);
#pragma unroll
  for (int i = 0; i < 8; i++) { a[i] = z; b[i] = z; }
  i32x4* l = (i32x4*)(lowC + (size_t)idx * 16);
  l[0] = z; l[1] = z;
}

// ---------------------------------------------------------------------------
// Weight normalization.
// blocks 0..63:   conv1 -> w1n[oc][k], k = kw*16+ch
// blocks 64..575: 8 layers x 64 oc -> wln[l][tap][oc][ic]  (edge path)
//                 AND wfrag fragment-major: [l][tap][ks][nt][lane][j]
// block 576:      last conv -> wlfrag bf16 fragment-major [tap][ks][lane][j],
//                 only n=0 (lane&15==0) populated.
// ---------------------------------------------------------------------------
__global__ __launch_bounds__(256) void wnorm_kernel(
    const float* v_h, const float* g_h,
    const float* vs, const float* gs,
    const float* v_last, const float* g_last,
    unsigned short* w1n, unsigned short* wln, unsigned short* wfrag,
    unsigned short* wlfrag) {
  __shared__ float red[256];
  int bid = blockIdx.x, tid = threadIdx.x;
  if (bid < 64) {
    int oc = bid;
    const float* v = v_h + oc * 98;       // [ch][kw] = [14][7]
    float s = 0.f;
    for (int i = tid; i < 98; i += 256) s += v[i] * v[i];
    red[tid] = s; __syncthreads();
    for (int off = 128; off > 0; off >>= 1) { if (tid < off) red[tid] += red[tid + off]; __syncthreads(); }
    float scale = g_h[oc] / sqrtf(red[0]);
    for (int k = tid; k < 128; k += 256) {
      int kw = k >> 4, ch = k & 15;
      unsigned short val = 0;
      if (kw < 7 && ch < 14) val = f2bf(v[ch * 7 + kw] * scale);
      w1n[oc * 128 + k] = val;
    }
  } else if (bid < 576) {
    int l = (bid - 64) >> 6, oc = (bid - 64) & 63;
    const float* v = vs + ((size_t)(l * 64 + oc)) * 576;  // [ic][kh][kw]
    float s = 0.f;
    for (int i = tid; i < 576; i += 256) s += v[i] * v[i];
    red[tid] = s; __syncthreads();
    for (int off = 128; off > 0; off >>= 1) { if (tid < off) red[tid] += red[tid + off]; __syncthreads(); }
    float scale = gs[l * 64 + oc] / sqrtf(red[0]);
    int nt = oc >> 4, lr = oc & 15;
    for (int i = tid; i < 576; i += 256) {
      int ic = i / 9, tap = i - ic * 9;
      unsigned short val = f2bf(v[i] * scale);
      wln[(((size_t)l * 9 + tap) * 64 + oc) * 64 + ic] = val;
      int ks = ic >> 5, qq = (ic >> 3) & 3, j = ic & 7;
      wfrag[(size_t)l * 36864 + (((tap * 2 + ks) * 4 + nt) * 512)
            + (((qq << 4) | lr) * 8) + j] = val;
    }
  } else {
    const float* v = v_last;              // [ic][kh][kw], 576
    float s = 0.f;
    for (int i = tid; i < 576; i += 256) s += v[i] * v[i];
    red[tid] = s; __syncthreads();
    for (int off = 128; off > 0; off >>= 1) { if (tid < off) red[tid] += red[tid + off]; __syncthreads(); }
    float scale = g_last[0] / sqrtf(red[0]);
    // wlfrag[tap][ks][lane*8+j]: B frag for 16x16x32, only n=0 nonzero
    for (int i = tid; i < 9216; i += 256) {
      int tap = i >> 10;
      int ks  = (i >> 9) & 1;
      int idx = i & 511;
      int lane = idx >> 3, j = idx & 7;
      int lr = lane & 15, qq = lane >> 4;
      unsigned short val = 0;
      if (lr == 0) {
        int ic = ks * 32 + qq * 8 + j;
        val = f2bf(v[ic * 9 + tap] * scale);
      }
      wlfrag[(size_t)(tap * 2 + ks) * 512 + idx] = val;
    }
  }
}

// ---------------------------------------------------------------------------
// STFT: radix-2 DIT FFT in LDS; reflect pad + Hann fused into bit-rev load.
// ---------------------------------------------------------------------------
__global__ __launch_bounds__(256) void stft_kernel(const float* __restrict__ x,
                                                   float* __restrict__ spec) {
  __shared__ float re[512];
  __shared__ float im[512];
  int bid = blockIdx.x;
  int b = bid / 257, fr = bid % 257;
  const float* xb = x + (size_t)b * 65536;
  int tid = threadIdx.x;
  for (int ii = 0; ii < 2; ii++) {
    int n = tid + ii * 256;
    int s = __brev((unsigned)n) >> 23;
    int j = fr * 256 + s - 256;
    int ja = j < 0 ? -j : (j >= 65536 ? 131070 - j : j);
    float w = 0.5f - 0.5f * __cosf(6.283185307179586f * (float)s / 512.0f);
    re[n] = xb[ja] * w;
    im[n] = 0.f;
  }
  __syncthreads();
  for (int st = 0; st < 9; st++) {
    int half = 1 << st;
    int p = tid & (half - 1);
    int g = tid >> st;
    int i0 = (g << (st + 1)) + p;
    int i1 = i0 + half;
    float ang = -6.283185307179586f * (float)p / (float)(2 << st);
    float sv, cv; __sincosf(ang, &sv, &cv);
    float br = re[i1], bi = im[i1];
    float tr = cv * br - sv * bi;
    float ti = cv * bi + sv * br;
    float ar = re[i0], ai = im[i0];
    re[i1] = ar - tr; im[i1] = ai - ti;
    re[i0] = ar + tr; im[i0] = ai + ti;
    __syncthreads();
  }
  for (int k = tid; k < 257; k += 256) {
    float* o = spec + (((size_t)b * 257 + fr) * 257 + k) * 2;
    o[0] = re[k];
    o[1] = im[k];
  }
}

// ---------------------------------------------------------------------------
// Harmonic lowering -> lowC canvas [b][f+8][t+8][16] (ch14,15 = 0), bf16.
// ---------------------------------------------------------------------------
__global__ __launch_bounds__(256) void lower_kernel(const float* __restrict__ spec,
                                                    unsigned short* __restrict__ lowC) {
  int idx = blockIdx.x * 256 + threadIdx.x;
  if (idx >= 4 * 66049) return;
  int b = idx / 66049, r = idx % 66049, f = r / 257, t = r % 257;
  const float shifts[7] = {1945.9101090932196f, 1252.7629684953681f, 847.2978603872037f,
                           559.6157879354227f, 336.4722366212129f, 154.15067982725836f, 0.0f};
  const float* sp = spec + ((size_t)(b * 257 + t)) * 257 * 2;
  unsigned short* lp = lowC + (((size_t)b * HCV + f + 8) * TCV + t + 8) * 16;
  unsigned w[8];
  for (int kf = 0; kf < 7; kf++) {
    float src = (float)f - shifts[kf];
    float lo = floorf(src);
    int li = (int)lo;
    float fr = src - lo;
    float g0r = 0.f, g0i = 0.f, g1r = 0.f, g1i = 0.f;
    if (li >= 0 && li < 257) { g0r = sp[li * 2]; g0i = sp[li * 2 + 1]; }
    if (li + 1 >= 0 && li + 1 < 257) { g1r = sp[(li + 1) * 2]; g1i = sp[(li + 1) * 2 + 1]; }
    float vr = (1.f - fr) * g0r + fr * g1r;
    float vi = (1.f - fr) * g0i + fr * g1i;
    w[kf] = (unsigned)f2bf(vr) | ((unsigned)f2bf(vi) << 16);
  }
  w[7] = 0;
  ((i32x4*)lp)[0] = i32x4{(int)w[0], (int)w[1], (int)w[2], (int)w[3]};
  ((i32x4*)lp)[1] = i32x4{(int)w[4], (int)w[5], (int)w[6], (int)w[7]};
}

// ---------------------------------------------------------------------------
// conv1: 14->64, 1x7, pad 3.  Block = (b,f) row.  B in registers (from
// swizzled LDS), A direct from global (im2col rows contiguous in NHWC16).
// Writes 64-channel canvas.
// ---------------------------------------------------------------------------
__global__ __launch_bounds__(256) void conv1_kernel(const unsigned short* __restrict__ lowC,
                                                    const unsigned short* __restrict__ w1n,
                                                    const float* __restrict__ b_h,
                                                    unsigned short* __restrict__ outc) {
  __shared__ unsigned short Bl[64 * 128];
  int bid = blockIdx.x;
  int f = bid % 257, b = bid / 257;
  int tid = threadIdx.x;
  for (int i = tid; i < 1024; i += 256) {
    int row = i >> 4, c = i & 15;
    *(i32x4*)&Bl[row * 128 + ((c ^ (row & 7)) * 8)] = ((const i32x4*)w1n)[i];
  }
  __syncthreads();
  int lane = tid & 63, wv = tid >> 6;
  int lrow = lane & 15, q = lane >> 4;
  bf16x8 bf[4][4];
#pragma unroll
  for (int ks = 0; ks < 4; ks++)
#pragma unroll
    for (int nt = 0; nt < 4; nt++) {
      int rrow = nt * 16 + lrow;
      int c = ks * 4 + q;
      bf[ks][nt] = *(const bf16x8*)&Bl[rrow * 128 + ((c ^ (lrow & 7)) * 8)];
    }
  const unsigned short* lrowp = lowC + ((size_t)(b * HCV + f + 8)) * TCV * 16;
  unsigned short* orow = outc + ((size_t)(b * HCV + f + 8)) * TCV * 64;
  float bv[4];
#pragma unroll
  for (int nt = 0; nt < 4; nt++) bv[nt] = b_h[nt * 16 + lrow];

  for (int tile = 0; tile < 5; tile++) {
    if (tile == 4 && wv != 0) break;
    int tbase = (tile < 4) ? (wv * 64 + tile * 16) : 256;
    f32x4 acc[4] = {f32x4{0,0,0,0}, f32x4{0,0,0,0}, f32x4{0,0,0,0}, f32x4{0,0,0,0}};
    const unsigned short* ap = lrowp + (size_t)(tbase + lrow + 5) * 16;
#pragma unroll
    for (int ks = 0; ks < 4; ks++) {
      bf16x8 a = *(const bf16x8*)&ap[ks * 32 + q * 8];
#pragma unroll
      for (int nt = 0; nt < 4; nt++)
        acc[nt] = __builtin_amdgcn_mfma_f32_16x16x32_bf16(a, bf[ks][nt], acc[nt], 0, 0, 0);
    }
    int tb = tbase + q * 4;
#pragma unroll
    for (int rg = 0; rg < 4; rg++) {
      int t = tb + rg;
      if (t < 257) {
#pragma unroll
        for (int nt = 0; nt < 4; nt++) {
          int oc = nt * 16 + lrow;
          float v = acc[nt][rg] + bv[nt];
          v = v > 0.f ? v : 0.2f * v;
          orow[(size_t)(t + 8) * 64 + oc] = f2bf(v);
        }
      }
    }
  }
}

// ---------------------------------------------------------------------------
// Dilated 3x3 conv 64->64 + bias + leaky.  Both operands in LDS.
// Blocks [0,257): edge path (t=256), wave wv = batch  -- first, no tail.
// Blocks [257, 257+1032): main.  (bid-257)&7 -> (b, fh), f = fh*129 + rest.
//   Per kh: stage X row (273x64, 34.9KB, XOR-swizzled) once; W phased
//   per-tap through double-buffered 2x8KB fragment-major slabs (512 i32x4
//   each = 2 per thread).  LDS 50.1KB -> 3 blocks/CU.  Wave M=64, N=64.
// ---------------------------------------------------------------------------
__global__ __launch_bounds__(256, 3) void conv3_kernel(const unsigned short* __restrict__ inc,
                                                       const unsigned short* __restrict__ wln,
                                                       const unsigned short* __restrict__ wfrag,
                                                       const float* __restrict__ bias,
                                                       unsigned short* __restrict__ outc,
                                                       int d) {
  __shared__ unsigned short Xs[273 * 64];      // 34.9KB, XOR-chunk swizzled
  __shared__ unsigned short Wl[2][4096];       // 2 x 8KB frag-major W slabs
  int bid = blockIdx.x;
  int tid = threadIdx.x;
  int lane = tid & 63, wv = tid >> 6;

  if (bid < 257) {
    // ---- edge path: t = 256; wave wv = batch ----
    int f = bid;
    int b = wv;
    int oc = lane;
    float acc = 0.f;
#pragma unroll
    for (int tap = 0; tap < 9; tap++) {
      int kh = tap / 3, kw = tap - kh * 3;
      int row = f + 8 + (kh - 1) * d;
      int ct = 264 + (kw - 1) * d;
      const unsigned short* xp = &inc[(((size_t)b * HCV + row) * TCV + ct) * 64];
      const unsigned short* wp = &wln[(size_t)(tap * 64 + oc) * 64];
      for (int icq = 0; icq < 8; icq++) {
        i32x4 xv = *(const i32x4*)&xp[icq * 8];
        i32x4 wq = *(const i32x4*)&wp[icq * 8];
#pragma unroll
        for (int j = 0; j < 4; j++)
          acc += bflo(xv[j]) * bflo(wq[j]) + bfhi(xv[j]) * bfhi(wq[j]);
      }
    }
    acc += bias[oc];
    acc = acc > 0.f ? acc : 0.2f * acc;
    outc[(((size_t)b * HCV + f + 8) * TCV + 264) * 64 + oc] = f2bf(acc);
    return;
  }

  int mb = bid - 257;
  int g = mb & 7;
  int b = g >> 1, fh = g & 1;
  int f = fh * 129 + (mb >> 3);
  if (f > 256) return;                        // 4 spill blocks (fh=1, fi=128)
  int lrow = lane & 15, q = lane >> 4;

  f32x4 acc[4][4];   // [mt][nt]
#pragma unroll
  for (int mt = 0; mt < 4; mt++)
#pragma unroll
    for (int nt = 0; nt < 4; nt++) acc[mt][nt] = f32x4{0,0,0,0};

  const size_t brow = (size_t)b * HCV;
  const int tbase0 = wv * 64;                 // wave's M-base in t (0..255 out)
#pragma unroll
  for (int kh = 0; kh < 3; kh++) {
    if (kh) __syncthreads();                  // prior phase's LDS reads done
    // stage input row (273 x 64ch): 2184 i32x4, coalesced, XOR-swizzled
    const i32x4* rowp = (const i32x4*)(inc + (brow + f + 8 + (kh - 1) * d) * TCV * 64);
    for (int i = tid; i < 2184; i += 256) {
      int t = i >> 3, c = i & 7;
      *(i32x4*)&Xs[t * 64 + ((c ^ (t & 7)) * 8)] = rowp[i];
    }
    // stage W slab for kw=0 into buffer 0: 512 i32x4 = 2 per thread
    {
      const i32x4* wsrc = (const i32x4*)(wfrag + (size_t)((kh * 3 + 0) * 8) * 512);
      ((i32x4*)&Wl[0][0])[tid] = wsrc[tid];
      ((i32x4*)&Wl[0][0])[tid + 256] = wsrc[tid + 256];
    }
    __syncthreads();
#pragma unroll
    for (int kw = 0; kw < 3; kw++) {
      int buf = kw & 1;
      if (kw < 2) {
        const i32x4* wsrc = (const i32x4*)(wfrag + (size_t)((kh * 3 + kw + 1) * 8) * 512);
        ((i32x4*)&Wl[buf ^ 1][0])[tid] = wsrc[tid];
        ((i32x4*)&Wl[buf ^ 1][0])[tid + 256] = wsrc[tid + 256];
      }
      int tshift = 8 + (kw - 1) * d;          // input col for output t=0
#pragma unroll
      for (int ks = 0; ks < 2; ks++) {
        bf16x8 bb[4];
#pragma unroll
        for (int nt = 0; nt < 4; nt++)
          bb[nt] = *(const bf16x8*)&Wl[buf][(ks * 4 + nt) * 512 + lane * 8];
        bf16x8 av[4];
#pragma unroll
        for (int mt = 0; mt < 4; mt++) {
          int t = tshift + tbase0 + mt * 16 + lrow;
          av[mt] = *(const bf16x8*)&Xs[t * 64 + (((ks * 4 + q) ^ (t & 7)) * 8)];
        }
#pragma unroll
        for (int nt = 0; nt < 4; nt++)
#pragma unroll
          for (int mt = 0; mt < 4; mt++)
            acc[mt][nt] = __builtin_amdgcn_mfma_f32_16x16x32_bf16(av[mt], bb[nt], acc[mt][nt], 0, 0, 0);
      }
      if (kw < 2) __syncthreads();            // W slab ready / readers done
    }
  }

  unsigned short* orow = outc + ((brow + f + 8) * TCV + 8) * 64;
#pragma unroll
  for (int mt = 0; mt < 4; mt++) {
    int tb = tbase0 + mt * 16 + q * 4;
#pragma unroll
    for (int rg = 0; rg < 4; rg++) {
      int t = tb + rg;
#pragma unroll
      for (int nt = 0; nt < 4; nt++) {   // nt innermost: 4x32B of one 128B row
        int oc = nt * 16 + lrow;
        float v = acc[mt][nt][rg] + bias[oc];
        v = v > 0.f ? v : 0.2f * v;
        orow[(size_t)t * 64 + oc] = f2bf(v);
      }
    }
  }
}

// ---------------------------------------------------------------------------
// Last conv 64->1, 3x3, pad 1 -> d_out.  conv3 anatomy: (b,f)-row blocks
// with XCD mapping, X staged per kh into XOR-swizzled LDS, MFMA N=16 with
// only n=0 populated (wlfrag, 18KB L1-hot).  Wave M=64; wave 0 runs a 5th
// masked m-tile for t=256 (clamped in-bounds Xs reads, only t=256 stored).
// ---------------------------------------------------------------------------
__global__ __launch_bounds__(256, 4) void last_kernel(const unsigned short* __restrict__ inc,
                                                      const unsigned short* __restrict__ wlfrag,
                                                      const float* __restrict__ b_last,
                                                      float* __restrict__ out) {
  __shared__ unsigned short Xs[273 * 64];      // 34.9KB, XOR-chunk swizzled
  int bid = blockIdx.x;
  int tid = threadIdx.x;
  int lane = tid & 63, wv = tid >> 6;
  int g = bid & 7;
  int b = g >> 1, fh = g & 1;
  int f = fh * 129 + (bid >> 3);
  if (f > 256) return;                        // 4 spill blocks
  int lrow = lane & 15, q = lane >> 4;

  f32x4 acc[5];   // 4 regular m-tiles + 5th (t=256, wave 0 only)
#pragma unroll
  for (int mt = 0; mt < 5; mt++) acc[mt] = f32x4{0,0,0,0};

  const size_t brow = (size_t)b * HCV;
  const int tbase0 = wv * 64;
  int nmt = (wv == 0) ? 5 : 4;
#pragma unroll
  for (int kh = 0; kh < 3; kh++) {
    if (kh) __syncthreads();
    const i32x4* rowp = (const i32x4*)(inc + (brow + f + 8 + (kh - 1)) * TCV * 64);
    for (int i = tid; i < 2184; i += 256) {
      int t = i >> 3, c = i & 7;
      *(i32x4*)&Xs[t * 64 + ((c ^ (t & 7)) * 8)] = rowp[i];
    }
    __syncthreads();
#pragma unroll
    for (int kw = 0; kw < 3; kw++) {
      int tap = kh * 3 + kw;
      int tshift = 8 + (kw - 1);
#pragma unroll
      for (int ks = 0; ks < 2; ks++) {
        bf16x8 bb = *(const bf16x8*)&wlfrag[(size_t)(tap * 2 + ks) * 512 + lane * 8];
        for (int mt = 0; mt < nmt; mt++) {
          int tt = (mt < 4) ? (tshift + tbase0 + mt * 16 + lrow)
                            : (tshift + 256 + lrow);
          if (tt > 272) tt = 272;             // clamp (garbage rows unused)
          bf16x8 a = *(const bf16x8*)&Xs[tt * 64 + (((ks * 4 + q) ^ (tt & 7)) * 8)];
          acc[mt] = __builtin_amdgcn_mfma_f32_16x16x32_bf16(a, bb, acc[mt], 0, 0, 0);
        }
      }
    }
  }

  float bl = b_last[0];
  float* orow = out + (size_t)b * 66049 + (size_t)f * 257;
  if (lrow == 0) {                            // only oc=0 column is real
    for (int mt = 0; mt < nmt; mt++) {
      int tb = ((mt < 4) ? (tbase0 + mt * 16) : 256) + q * 4;
#pragma unroll
      for (int rg = 0; rg < 4; rg++) {
        int t = tb + rg;
        if (t < 257) orow[t] = acc[mt][rg] + bl;
      }
    }
  }
}

extern "C" void kernel_launch(void* const* d_in, const int* in_sizes, int n_in,
                              void* d_out, int out_size, void* d_ws, size_t ws_size,
                              hipStream_t stream) {
  const float* x      = (const float*)d_in[0];
  const float* v_h    = (const float*)d_in[1];
  const float* g_h    = (const float*)d_in[2];
  const float* b_h    = (const float*)d_in[3];
  const float* vs     = (const float*)d_in[4];
  const float* gs     = (const float*)d_in[5];
  const float* bs     = (const float*)d_in[6];
  const float* v_last = (const float*)d_in[7];
  const float* g_last = (const float*)d_in[8];
  const float* b_last = (const float*)d_in[9];

  char* ws = (char*)d_ws;
  unsigned short* canvasA = (unsigned short*)ws;
  unsigned short* canvasB = (unsigned short*)(ws + CAN_BYTES);
  unsigned short* lowC    = canvasB;                         // aliased; re-zeroed after conv1
  float*          spec    = (float*)(ws + 2 * CAN_BYTES);
  unsigned short* w1n     = (unsigned short*)(ws + 2 * CAN_BYTES + SPEC_BYTES);
  unsigned short* wln     = (unsigned short*)(ws + 2 * CAN_BYTES + SPEC_BYTES + W1N_BYTES);
  unsigned short* wfrag   = (unsigned short*)(ws + 2 * CAN_BYTES + SPEC_BYTES + W1N_BYTES + WLN_BYTES);
  unsigned short* wlfrag  = (unsigned short*)(ws + 2 * CAN_BYTES + SPEC_BYTES + W1N_BYTES + WLN_BYTES + WFRAG_BYTES);
  float*          out     = (float*)d_out;

  halo_zero_kernel<<<(NBATCH * HCV * TCV + 255) / 256, 256, 0, stream>>>(canvasA, canvasB, lowC);
  wnorm_kernel<<<577, 256, 0, stream>>>(v_h, g_h, vs, gs, v_last, g_last, w1n, wln, wfrag, wlfrag);
  stft_kernel<<<4 * 257, 256, 0, stream>>>(x, spec);
  lower_kernel<<<(4 * 66049 + 255) / 256, 256, 0, stream>>>(spec, lowC);
  conv1_kernel<<<4 * 257, 256, 0, stream>>>(lowC, w1n, b_h, canvasA);

  // lowC occupied canvasB's first bytes: restore zeros (halo incl.) before
  // layer 1 writes canvasB
  hipMemsetAsync(canvasB, 0, LOWC_BYTES, stream);

  unsigned short* cur = canvasA;
  unsigned short* nxt = canvasB;
  for (int l = 0; l < 8; l++) {
    int d = l + 1;
    const unsigned short* w  = wln + (size_t)l * 9 * 64 * 64;
    const unsigned short* wf = wfrag + (size_t)l * 36864;
    const float* bb = bs + l * 64;
    conv3_kernel<<<257 + 1032, 256, 0, stream>>>(cur, w, wf, bb, nxt, d);
    unsigned short* tmp = cur; cur = nxt; nxt = tmp;
  }

  last_kernel<<<1032, 256, 0, stream>>>(cur, wlfrag, b_last, out);
}

// Round 17
// 455.296 us; speedup vs baseline: 1.0523x; 1.0523x over previous
//
#include <hip/hip_runtime.h>
#include <stdint.h>

// ---------------------------------------------------------------------------
// HarmonicStructureDiscriminator on MI355X (gfx950)
// STFT(512/256) -> log-shift lower (KF=7) -> conv1x7(14->64)
//   -> 8x dilated conv3x3(64->64, d=1..8) -> conv3x3(64->1)
// Round 17 = R16 + SWIZZLED CANVAS + global_load_lds staging:
// canvas stores chunk c of column t at position c^(t&7) (writers swizzle,
// readers unswizzle -- conv3/last A-frag reads already used this formula).
// The LDS X-row image is then byte-identical to the global row, so conv3 and
// last stage X and W via __builtin_amdgcn_global_load_lds width=16 (async
// DMA, zero ds_writes, no VGPR round-trip -- the m97 lever).
// LDS 52.2KB -> 3 blocks/CU.  Structure otherwise identical to R15/R16.
// mfma_f32_16x16x32_bf16: A[m=lane&15][k=q*8+j], B[n=lane&15][k],
// D col=lane&15,row=q*4+reg (m89/m101-verified).
// ---------------------------------------------------------------------------

typedef __attribute__((ext_vector_type(8))) short bf16x8;
typedef __attribute__((ext_vector_type(4))) float f32x4;
typedef __attribute__((ext_vector_type(4))) int   i32x4;

#define HCV 273
#define TCV 273
#define NBATCH 4

static constexpr size_t CAN_BYTES  = (size_t)NBATCH * HCV * TCV * 64 * 2;  // 38,158,848
static constexpr size_t LOWC_BYTES = (size_t)NBATCH * HCV * TCV * 16 * 2;  // 9,539,712
static constexpr size_t SPEC_BYTES = (size_t)NBATCH * 257 * 257 * 2 * 4;
static constexpr size_t W1N_BYTES  = 64 * 128 * 2;
static constexpr size_t WLN_BYTES  = 8 * 9 * 64 * 64 * 2;
static constexpr size_t WFRAG_BYTES = 8 * 9 * 2 * 4 * 512 * 2;             // 589,824
static constexpr size_t WLFRAG_BYTES = 9 * 2 * 512 * 2;                    // 18,432

static __device__ __forceinline__ unsigned short f2bf(float f) {
  union { float f; unsigned u; } v; v.f = f;
  unsigned r = v.u + 0x7FFFu + ((v.u >> 16) & 1u);   // RNE
  return (unsigned short)(r >> 16);
}
static __device__ __forceinline__ float bflo(int u) {
  union { unsigned u; float f; } v; v.u = ((unsigned)u) << 16; return v.f;
}
static __device__ __forceinline__ float bfhi(int u) {
  union { unsigned u; float f; } v; v.u = ((unsigned)u) & 0xFFFF0000u; return v.f;
}

// async global->LDS DMA, 16B per lane; dest = lds base + lane*16 (m104).
static __device__ __forceinline__ void gl16(const void* g, void* l) {
  __builtin_amdgcn_global_load_lds(
      (const __attribute__((address_space(1))) void*)g,
      (__attribute__((address_space(3))) void*)l, 16, 0, 0);
}

// ---------------------------------------------------------------------------
// Zero ONLY the canvas halos (zeros are swizzle-invariant).
// ---------------------------------------------------------------------------
__global__ __launch_bounds__(256) void halo_zero_kernel(unsigned short* cA,
                                                        unsigned short* cB,
                                                        unsigned short* lowC) {
  int idx = blockIdx.x * 256 + threadIdx.x;
  if (idx >= NBATCH * HCV * TCV) return;
  int pos = idx % (HCV * TCV);
  int row = pos / TCV, col = pos % TCV;
  bool halo = (row < 8) | (row > 264) | (col < 8) | (col > 264);
  if (!halo) return;
  i32x4 z = {0, 0, 0, 0};
  i32x4* a = (i32x4*)(cA + (size_t)idx * 64);
  i32x4* b = (i32x4*)(cB + (size_t)idx * 64);
#pragma unroll
  for (int i = 0; i < 8; i++) { a[i] = z; b[i] = z; }
  i32x4* l = (i32x4*)(lowC + (size_t)idx * 16);
  l[0] = z; l[1] = z;
}

// ---------------------------------------------------------------------------
// Weight normalization (unchanged from R16).
// ---------------------------------------------------------------------------
__global__ __launch_bounds__(256) void wnorm_kernel(
    const float* v_h, const float* g_h,
    const float* vs, const float* gs,
    const float* v_last, const float* g_last,
    unsigned short* w1n, unsigned short* wln, unsigned short* wfrag,
    unsigned short* wlfrag) {
  __shared__ float red[256];
  int bid = blockIdx.x, tid = threadIdx.x;
  if (bid < 64) {
    int oc = bid;
    const float* v = v_h + oc * 98;       // [ch][kw] = [14][7]
    float s = 0.f;
    for (int i = tid; i < 98; i += 256) s += v[i] * v[i];
    red[tid] = s; __syncthreads();
    for (int off = 128; off > 0; off >>= 1) { if (tid < off) red[tid] += red[tid + off]; __syncthreads(); }
    float scale = g_h[oc] / sqrtf(red[0]);
    for (int k = tid; k < 128; k += 256) {
      int kw = k >> 4, ch = k & 15;
      unsigned short val = 0;
      if (kw < 7 && ch < 14) val = f2bf(v[ch * 7 + kw] * scale);
      w1n[oc * 128 + k] = val;
    }
  } else if (bid < 576) {
    int l = (bid - 64) >> 6, oc = (bid - 64) & 63;
    const float* v = vs + ((size_t)(l * 64 + oc)) * 576;  // [ic][kh][kw]
    float s = 0.f;
    for (int i = tid; i < 576; i += 256) s += v[i] * v[i];
    red[tid] = s; __syncthreads();
    for (int off = 128; off > 0; off >>= 1) { if (tid < off) red[tid] += red[tid + off]; __syncthreads(); }
    float scale = gs[l * 64 + oc] / sqrtf(red[0]);
    int nt = oc >> 4, lr = oc & 15;
    for (int i = tid; i < 576; i += 256) {
      int ic = i / 9, tap = i - ic * 9;
      unsigned short val = f2bf(v[i] * scale);
      wln[(((size_t)l * 9 + tap) * 64 + oc) * 64 + ic] = val;
      int ks = ic >> 5, qq = (ic >> 3) & 3, j = ic & 7;
      wfrag[(size_t)l * 36864 + (((tap * 2 + ks) * 4 + nt) * 512)
            + (((qq << 4) | lr) * 8) + j] = val;
    }
  } else {
    const float* v = v_last;              // [ic][kh][kw], 576
    float s = 0.f;
    for (int i = tid; i < 576; i += 256) s += v[i] * v[i];
    red[tid] = s; __syncthreads();
    for (int off = 128; off > 0; off >>= 1) { if (tid < off) red[tid] += red[tid + off]; __syncthreads(); }
    float scale = g_last[0] / sqrtf(red[0]);
    for (int i = tid; i < 9216; i += 256) {
      int tap = i >> 10;
      int ks  = (i >> 9) & 1;
      int idx = i & 511;
      int lane = idx >> 3, j = idx & 7;
      int lr = lane & 15, qq = lane >> 4;
      unsigned short val = 0;
      if (lr == 0) {
        int ic = ks * 32 + qq * 8 + j;
        val = f2bf(v[ic * 9 + tap] * scale);
      }
      wlfrag[(size_t)(tap * 2 + ks) * 512 + idx] = val;
    }
  }
}

// ---------------------------------------------------------------------------
// STFT (unchanged).
// ---------------------------------------------------------------------------
__global__ __launch_bounds__(256) void stft_kernel(const float* __restrict__ x,
                                                   float* __restrict__ spec) {
  __shared__ float re[512];
  __shared__ float im[512];
  int bid = blockIdx.x;
  int b = bid / 257, fr = bid % 257;
  const float* xb = x + (size_t)b * 65536;
  int tid = threadIdx.x;
  for (int ii = 0; ii < 2; ii++) {
    int n = tid + ii * 256;
    int s = __brev((unsigned)n) >> 23;
    int j = fr * 256 + s - 256;
    int ja = j < 0 ? -j : (j >= 65536 ? 131070 - j : j);
    float w = 0.5f - 0.5f * __cosf(6.283185307179586f * (float)s / 512.0f);
    re[n] = xb[ja] * w;
    im[n] = 0.f;
  }
  __syncthreads();
  for (int st = 0; st < 9; st++) {
    int half = 1 << st;
    int p = tid & (half - 1);
    int g = tid >> st;
    int i0 = (g << (st + 1)) + p;
    int i1 = i0 + half;
    float ang = -6.283185307179586f * (float)p / (float)(2 << st);
    float sv, cv; __sincosf(ang, &sv, &cv);
    float br = re[i1], bi = im[i1];
    float tr = cv * br - sv * bi;
    float ti = cv * bi + sv * br;
    float ar = re[i0], ai = im[i0];
    re[i1] = ar - tr; im[i1] = ai - ti;
    re[i0] = ar + tr; im[i0] = ai + ti;
    __syncthreads();
  }
  for (int k = tid; k < 257; k += 256) {
    float* o = spec + (((size_t)b * 257 + fr) * 257 + k) * 2;
    o[0] = re[k];
    o[1] = im[k];
  }
}

// ---------------------------------------------------------------------------
// Harmonic lowering -> lowC (16ch, unswizzled; unchanged).
// ---------------------------------------------------------------------------
__global__ __launch_bounds__(256) void lower_kernel(const float* __restrict__ spec,
                                                    unsigned short* __restrict__ lowC) {
  int idx = blockIdx.x * 256 + threadIdx.x;
  if (idx >= 4 * 66049) return;
  int b = idx / 66049, r = idx % 66049, f = r / 257, t = r % 257;
  const float shifts[7] = {1945.9101090932196f, 1252.7629684953681f, 847.2978603872037f,
                           559.6157879354227f, 336.4722366212129f, 154.15067982725836f, 0.0f};
  const float* sp = spec + ((size_t)(b * 257 + t)) * 257 * 2;
  unsigned short* lp = lowC + (((size_t)b * HCV + f + 8) * TCV + t + 8) * 16;
  unsigned w[8];
  for (int kf = 0; kf < 7; kf++) {
    float src = (float)f - shifts[kf];
    float lo = floorf(src);
    int li = (int)lo;
    float fr = src - lo;
    float g0r = 0.f, g0i = 0.f, g1r = 0.f, g1i = 0.f;
    if (li >= 0 && li < 257) { g0r = sp[li * 2]; g0i = sp[li * 2 + 1]; }
    if (li + 1 >= 0 && li + 1 < 257) { g1r = sp[(li + 1) * 2]; g1i = sp[(li + 1) * 2 + 1]; }
    float vr = (1.f - fr) * g0r + fr * g1r;
    float vi = (1.f - fr) * g0i + fr * g1i;
    w[kf] = (unsigned)f2bf(vr) | ((unsigned)f2bf(vi) << 16);
  }
  w[7] = 0;
  ((i32x4*)lp)[0] = i32x4{(int)w[0], (int)w[1], (int)w[2], (int)w[3]};
  ((i32x4*)lp)[1] = i32x4{(int)w[4], (int)w[5], (int)w[6], (int)w[7]};
}

// ---------------------------------------------------------------------------
// conv1: 14->64, 1x7, pad 3.  Writes SWIZZLED canvas: chunk c of col cc at
// position c^(cc&7)  (cc = t+8, key = t&7).
// ---------------------------------------------------------------------------
__global__ __launch_bounds__(256) void conv1_kernel(const unsigned short* __restrict__ lowC,
                                                    const unsigned short* __restrict__ w1n,
                                                    const float* __restrict__ b_h,
                                                    unsigned short* __restrict__ outc) {
  __shared__ unsigned short Bl[64 * 128];
  int bid = blockIdx.x;
  int f = bid % 257, b = bid / 257;
  int tid = threadIdx.x;
  for (int i = tid; i < 1024; i += 256) {
    int row = i >> 4, c = i & 15;
    *(i32x4*)&Bl[row * 128 + ((c ^ (row & 7)) * 8)] = ((const i32x4*)w1n)[i];
  }
  __syncthreads();
  int lane = tid & 63, wv = tid >> 6;
  int lrow = lane & 15, q = lane >> 4;
  bf16x8 bf[4][4];
#pragma unroll
  for (int ks = 0; ks < 4; ks++)
#pragma unroll
    for (int nt = 0; nt < 4; nt++) {
      int rrow = nt * 16 + lrow;
      int c = ks * 4 + q;
      bf[ks][nt] = *(const bf16x8*)&Bl[rrow * 128 + ((c ^ (lrow & 7)) * 8)];
    }
  const unsigned short* lrowp = lowC + ((size_t)(b * HCV + f + 8)) * TCV * 16;
  unsigned short* orow = outc + ((size_t)(b * HCV + f + 8)) * TCV * 64;
  float bv[4];
#pragma unroll
  for (int nt = 0; nt < 4; nt++) bv[nt] = b_h[nt * 16 + lrow];

  for (int tile = 0; tile < 5; tile++) {
    if (tile == 4 && wv != 0) break;
    int tbase = (tile < 4) ? (wv * 64 + tile * 16) : 256;
    f32x4 acc[4] = {f32x4{0,0,0,0}, f32x4{0,0,0,0}, f32x4{0,0,0,0}, f32x4{0,0,0,0}};
    const unsigned short* ap = lrowp + (size_t)(tbase + lrow + 5) * 16;
#pragma unroll
    for (int ks = 0; ks < 4; ks++) {
      bf16x8 a = *(const bf16x8*)&ap[ks * 32 + q * 8];
#pragma unroll
      for (int nt = 0; nt < 4; nt++)
        acc[nt] = __builtin_amdgcn_mfma_f32_16x16x32_bf16(a, bf[ks][nt], acc[nt], 0, 0, 0);
    }
    int tb = tbase + q * 4;
#pragma unroll
    for (int rg = 0; rg < 4; rg++) {
      int t = tb + rg;
      if (t < 257) {
#pragma unroll
        for (int nt = 0; nt < 4; nt++) {
          int oc = nt * 16 + lrow;
          float v = acc[nt][rg] + bv[nt];
          v = v > 0.f ? v : 0.2f * v;
          int pos = (((oc >> 3) ^ (t & 7)) << 3) | (oc & 7);   // cc=t+8, key=t&7
          orow[(size_t)(t + 8) * 64 + pos] = f2bf(v);
        }
      }
    }
  }
}

// ---------------------------------------------------------------------------
// Dilated 3x3 conv 64->64 + bias + leaky.  Swizzled canvas; X and W staged
// by global_load_lds (linear DMA, no ds_writes).  LDS 52.2KB -> 3 blk/CU.
// Blocks [0,257): edge path (t=256).  Blocks [257,1289): main rows.
// ---------------------------------------------------------------------------
__global__ __launch_bounds__(256, 3) void conv3_kernel(const unsigned short* __restrict__ inc,
                                                       const unsigned short* __restrict__ wln,
                                                       const unsigned short* __restrict__ wfrag,
                                                       const float* __restrict__ bias,
                                                       unsigned short* __restrict__ outc,
                                                       int d) {
  __shared__ unsigned short Xs[273 * 64 + 448];  // +56 pad chunks (DMA tail)
  __shared__ unsigned short Wl[2][4096];         // 2 x 8KB frag-major W slabs
  int bid = blockIdx.x;
  int tid = threadIdx.x;
  int lane = tid & 63, wv = tid >> 6;

  if (bid < 257) {
    // ---- edge path: t = 256; wave wv = batch; canvas is swizzled ----
    int f = bid;
    int b = wv;
    int oc = lane;
    float acc = 0.f;
#pragma unroll
    for (int tap = 0; tap < 9; tap++) {
      int kh = tap / 3, kw = tap - kh * 3;
      int row = f + 8 + (kh - 1) * d;
      int ct = 264 + (kw - 1) * d;
      const unsigned short* xp = &inc[(((size_t)b * HCV + row) * TCV + ct) * 64];
      const unsigned short* wp = &wln[(size_t)(tap * 64 + oc) * 64];
      for (int icq = 0; icq < 8; icq++) {
        int p = icq ^ (ct & 7);
        i32x4 xv = *(const i32x4*)&xp[p * 8];
        i32x4 wq = *(const i32x4*)&wp[icq * 8];
#pragma unroll
        for (int j = 0; j < 4; j++)
          acc += bflo(xv[j]) * bflo(wq[j]) + bfhi(xv[j]) * bfhi(wq[j]);
      }
    }
    acc += bias[oc];
    acc = acc > 0.f ? acc : 0.2f * acc;
    // col 264: key = 0 -> unswizzled position
    outc[(((size_t)b * HCV + f + 8) * TCV + 264) * 64 + oc] = f2bf(acc);
    return;
  }

  int mb = bid - 257;
  int g = mb & 7;
  int b = g >> 1, fh = g & 1;
  int f = fh * 129 + (mb >> 3);
  if (f > 256) return;                        // 4 spill blocks (fh=1, fi=128)
  int lrow = lane & 15, q = lane >> 4;

  f32x4 acc[4][4];   // [mt][nt]
#pragma unroll
  for (int mt = 0; mt < 4; mt++)
#pragma unroll
    for (int nt = 0; nt < 4; nt++) acc[mt][nt] = f32x4{0,0,0,0};

  const size_t brow = (size_t)b * HCV;
  const int tbase0 = wv * 64;                 // wave's M-base in t (0..255 out)
  const int wvbase = tid & 0xC0;              // wv*64, wave-uniform
#pragma unroll
  for (int kh = 0; kh < 3; kh++) {
    if (kh) __syncthreads();                  // prior phase's LDS reads done
    // stage input row (2184 x 16B chunks) via async DMA, linear copy
    const unsigned short* rowc = inc + (brow + f + 8 + (kh - 1) * d) * TCV * 64;
    for (int base = 0; base < 2184; base += 256) {
      int i = base + tid;
      if (i < 2184)
        gl16(rowc + (size_t)i * 8, &Xs[(base + wvbase) * 8]);
    }
    // stage W slab for kw=0 into buffer 0 (512 chunks)
    {
      const unsigned short* wsrc = wfrag + (size_t)((kh * 3 + 0) * 8) * 512;
      gl16(wsrc + (size_t)tid * 8, &Wl[0][wvbase * 8]);
      gl16(wsrc + (size_t)(tid + 256) * 8, &Wl[0][(256 + wvbase) * 8]);
    }
    __syncthreads();
#pragma unroll
    for (int kw = 0; kw < 3; kw++) {
      int buf = kw & 1;
      if (kw < 2) {
        const unsigned short* wsrc = wfrag + (size_t)((kh * 3 + kw + 1) * 8) * 512;
        gl16(wsrc + (size_t)tid * 8, &Wl[buf ^ 1][wvbase * 8]);
        gl16(wsrc + (size_t)(tid + 256) * 8, &Wl[buf ^ 1][(256 + wvbase) * 8]);
      }
      int tshift = 8 + (kw - 1) * d;          // input col for output t=0
#pragma unroll
      for (int ks = 0; ks < 2; ks++) {
        bf16x8 bb[4];
#pragma unroll
        for (int nt = 0; nt < 4; nt++)
          bb[nt] = *(const bf16x8*)&Wl[buf][(ks * 4 + nt) * 512 + lane * 8];
        bf16x8 av[4];
#pragma unroll
        for (int mt = 0; mt < 4; mt++) {
          int t = tshift + tbase0 + mt * 16 + lrow;
          av[mt] = *(const bf16x8*)&Xs[t * 64 + (((ks * 4 + q) ^ (t & 7)) * 8)];
        }
#pragma unroll
        for (int nt = 0; nt < 4; nt++)
#pragma unroll
          for (int mt = 0; mt < 4; mt++)
            acc[mt][nt] = __builtin_amdgcn_mfma_f32_16x16x32_bf16(av[mt], bb[nt], acc[mt][nt], 0, 0, 0);
      }
      if (kw < 2) __syncthreads();            // W slab ready / readers done
    }
  }

  unsigned short* orow = outc + ((brow + f + 8) * TCV + 8) * 64;
#pragma unroll
  for (int mt = 0; mt < 4; mt++) {
    int tb = tbase0 + mt * 16 + q * 4;
#pragma unroll
    for (int rg = 0; rg < 4; rg++) {
      int t = tb + rg;
#pragma unroll
      for (int nt = 0; nt < 4; nt++) {
        int oc = nt * 16 + lrow;
        float v = acc[mt][nt][rg] + bias[oc];
        v = v > 0.f ? v : 0.2f * v;
        int pos = (((oc >> 3) ^ (t & 7)) << 3) | (oc & 7);   // cc=t+8, key=t&7
        orow[(size_t)t * 64 + pos] = f2bf(v);
      }
    }
  }
}

// ---------------------------------------------------------------------------
// Last conv 64->1 -> d_out.  Same anatomy; X staged via global_load_lds
// (canvas swizzled; A-read formula already matches).
// ---------------------------------------------------------------------------
__global__ __launch_bounds__(256, 4) void last_kernel(const unsigned short* __restrict__ inc,
                                                      const unsigned short* __restrict__ wlfrag,
                                                      const float* __restrict__ b_last,
                                                      float* __restrict__ out) {
  __shared__ unsigned short Xs[273 * 64 + 448];  // +pad for DMA tail
  int bid = blockIdx.x;
  int tid = threadIdx.x;
  int lane = tid & 63, wv = tid >> 6;
  int g = bid & 7;
  int b = g >> 1, fh = g & 1;
  int f = fh * 129 + (bid >> 3);
  if (f > 256) return;                        // 4 spill blocks
  int lrow = lane & 15, q = lane >> 4;
  const int wvbase = tid & 0xC0;

  f32x4 acc[5];   // 4 regular m-tiles + 5th (t=256, wave 0 only)
#pragma unroll
  for (int mt = 0; mt < 5; mt++) acc[mt] = f32x4{0,0,0,0};

  const size_t brow = (size_t)b * HCV;
  const int tbase0 = wv * 64;
  int nmt = (wv == 0) ? 5 : 4;
#pragma unroll
  for (int kh = 0; kh < 3; kh++) {
    if (kh) __syncthreads();
    const unsigned short* rowc = inc + (brow + f + 8 + (kh - 1)) * TCV * 64;
    for (int base = 0; base < 2184; base += 256) {
      int i = base + tid;
      if (i < 2184)
        gl16(rowc + (size_t)i * 8, &Xs[(base + wvbase) * 8]);
    }
    __syncthreads();
#pragma unroll
    for (int kw = 0; kw < 3; kw++) {
      int tap = kh * 3 + kw;
      int tshift = 8 + (kw - 1);
#pragma unroll
      for (int ks = 0; ks < 2; ks++) {
        bf16x8 bb = *(const bf16x8*)&wlfrag[(size_t)(tap * 2 + ks) * 512 + lane * 8];
        for (int mt = 0; mt < nmt; mt++) {
          int tt = (mt < 4) ? (tshift + tbase0 + mt * 16 + lrow)
                            : (tshift + 256 + lrow);
          if (tt > 272) tt = 272;             // clamp (garbage rows unused)
          bf16x8 a = *(const bf16x8*)&Xs[tt * 64 + (((ks * 4 + q) ^ (tt & 7)) * 8)];
          acc[mt] = __builtin_amdgcn_mfma_f32_16x16x32_bf16(a, bb, acc[mt], 0, 0, 0);
        }
      }
    }
  }

  float bl = b_last[0];
  float* orow = out + (size_t)b * 66049 + (size_t)f * 257;
  if (lrow == 0) {                            // only oc=0 column is real
    for (int mt = 0; mt < nmt; mt++) {
      int tb = ((mt < 4) ? (tbase0 + mt * 16) : 256) + q * 4;
#pragma unroll
      for (int rg = 0; rg < 4; rg++) {
        int t = tb + rg;
        if (t < 257) orow[t] = acc[mt][rg] + bl;
      }
    }
  }
}

extern "C" void kernel_launch(void* const* d_in, const int* in_sizes, int n_in,
                              void* d_out, int out_size, void* d_ws, size_t ws_size,
                              hipStream_t stream) {
  const float* x      = (const float*)d_in[0];
  const float* v_h    = (const float*)d_in[1];
  const float* g_h    = (const float*)d_in[2];
  const float* b_h    = (const float*)d_in[3];
  const float* vs     = (const float*)d_in[4];
  const float* gs     = (const float*)d_in[5];
  const float* bs     = (const float*)d_in[6];
  const float* v_last = (const float*)d_in[7];
  const float* g_last = (const float*)d_in[8];
  const float* b_last = (const float*)d_in[9];

  char* ws = (char*)d_ws;
  unsigned short* canvasA = (unsigned short*)ws;
  unsigned short* canvasB = (unsigned short*)(ws + CAN_BYTES);
  unsigned short* lowC    = canvasB;                         // aliased; re-zeroed after conv1
  float*          spec    = (float*)(ws + 2 * CAN_BYTES);
  unsigned short* w1n     = (unsigned short*)(ws + 2 * CAN_BYTES + SPEC_BYTES);
  unsigned short* wln     = (unsigned short*)(ws + 2 * CAN_BYTES + SPEC_BYTES + W1N_BYTES);
  unsigned short* wfrag   = (unsigned short*)(ws + 2 * CAN_BYTES + SPEC_BYTES + W1N_BYTES + WLN_BYTES);
  unsigned short* wlfrag  = (unsigned short*)(ws + 2 * CAN_BYTES + SPEC_BYTES + W1N_BYTES + WLN_BYTES + WFRAG_BYTES);
  float*          out     = (float*)d_out;

  halo_zero_kernel<<<(NBATCH * HCV * TCV + 255) / 256, 256, 0, stream>>>(canvasA, canvasB, lowC);
  wnorm_kernel<<<577, 256, 0, stream>>>(v_h, g_h, vs, gs, v_last, g_last, w1n, wln, wfrag, wlfrag);
  stft_kernel<<<4 * 257, 256, 0, stream>>>(x, spec);
  lower_kernel<<<(4 * 66049 + 255) / 256, 256, 0, stream>>>(spec, lowC);
  conv1_kernel<<<4 * 257, 256, 0, stream>>>(lowC, w1n, b_h, canvasA);

  // lowC occupied canvasB's first bytes: restore zeros (halo incl.) before
  // layer 1 writes canvasB
  hipMemsetAsync(canvasB, 0, LOWC_BYTES, stream);

  unsigned short* cur = canvasA;
  unsigned short* nxt = canvasB;
  for (int l = 0; l < 8; l++) {
    int d = l + 1;
    const unsigned short* w  = wln + (size_t)l * 9 * 64 * 64;
    const unsigned short* wf = wfrag + (size_t)l * 36864;
    const float* bb = bs + l * 64;
    conv3_kernel<<<257 + 1032, 256, 0, stream>>>(cur, w, wf, bb, nxt, d);
    unsigned short* tmp = cur; cur = nxt; nxt = tmp;
  }

  last_kernel<<<1032, 256, 0, stream>>>(cur, wlfrag, b_last, out);
}